// Round 11
// baseline (1635.395 us; speedup 1.0000x reference)
//
#include <hip/hip_runtime.h>
#include <hip/hip_cooperative_groups.h>
#include <stdint.h>
#include <math.h>

namespace cg = cooperative_groups;

// Problem constants
#define BN 4
#define VN 16384
#define KN 16
#define HN 4
#define NN (BN*VN)          // 65536 nodes total
#define EN (VN*KN)          // 262144 edges per batch
#define CAP 64              // inverse-adjacency bucket capacity (P(deg>64) ~ 1e-13)
#define NEGC (-1.0e9f)

typedef __attribute__((ext_vector_type(8))) short short8;
typedef __attribute__((ext_vector_type(4))) float floatx4;
typedef __attribute__((ext_vector_type(2))) float floatx2;
typedef unsigned short u16;
typedef unsigned int u32;

// ---------- workspace layout (bytes) ----------
#define OFF_H      0ull                     // h       bf16 [NN][64]    8 MB
#define OFF_M      8388608ull               // m       bf16 [NN][64]    8 MB (PERMUTED dim order)
#define OFF_T      16777216ull              // t_all fp8 u32[NN+1][64] 16.8 MB; REUSED as bucket u32[NN][64] (16MB)
#define OFF_SS     50331648ull              // ss      fp32 [NN][8]     2 MB (scores: [2hd+0]=src, [2hd+1]=dst)
#define OFF_NW     52428800ull              // node_w  fp32 [NN]      256 KB
#define OFF_NV     52690944ull              // nv      fp32 [2][NN]   512 KB
#define OFF_CNT    53215232ull              // cnt     u32  [NN]      256 KB
#define OFF_PG     53477376ull              // packed W_gat   32 KB
#define OFF_PZR    (OFF_PG  + 32768ull)     // packed Wz|Wr/Uz|Ur 32 KB
#define OFF_PC     (OFF_PZR + 32768ull)     // packed Wc/Uc   16 KB
#define OFF_PE1    (OFF_PC  + 16384ull)     // packed W_enc1 (K padded to 64) 8 KB
#define OFF_PE2    (OFF_PE1 + 8192ull)      // packed W_enc2  8 KB
#define OFF_PD1    (OFF_PE2 + 8192ull)      // packed W_dec1  8 KB
#define OFF_PAV    (OFF_PD1 + 8192ull)      // packed W_gat@a_{src,dst} 64x16  2 KB
// total ws use ~53.6 MB

__device__ __forceinline__ u16 f2bf(float x){
  union { float f; unsigned int u; } c; c.f = x;
  unsigned int r = c.u + 0x7fffu + ((c.u >> 16) & 1u);
  return (u16)(r >> 16);
}
__device__ __forceinline__ float bf2f(u32 s){
  union { unsigned int u; float f; } c; c.u = s << 16;
  return c.f;
}
__device__ __forceinline__ float sigm(float x){ return 1.0f/(1.0f+expf(-x)); }

union S8 { short8 v; u16 u[8]; };

// ================= weight pack kernel =================
// packed layout: flat elem e = ((ng*CN + c)*64 + lane)*8 + j holds Mat[k][n],
// k = c*32 + (lane>>4)*8 + j,  n = ng*16 + (lane&15),  CN = K/32.
// m is PERMUTED: m_perm[p] = m_std[(p&3)*16 + (p>>2)] -> un-permute its rows here.
// region 6 (pav): M[k][2hd+s] = sum_n W_gat[hd][k][n] * a_{s}[hd][n]
__global__ __launch_bounds__(256) void k_pack(
    const float* __restrict__ Wg,  const float* __restrict__ Wz, const float* __restrict__ Uz,
    const float* __restrict__ Wr,  const float* __restrict__ Ur, const float* __restrict__ Wc,
    const float* __restrict__ Uc,  const float* __restrict__ We1, const float* __restrict__ We2,
    const float* __restrict__ Wd1, const float* __restrict__ asrc, const float* __restrict__ adst,
    u16* __restrict__ pg, u16* __restrict__ pzr, u16* __restrict__ pc,
    u16* __restrict__ pe1, u16* __restrict__ pe2, u16* __restrict__ pd1,
    u16* __restrict__ pav)
{
  int e = blockIdx.x*256 + threadIdx.x;   // 0 .. 54271
  if (e >= 54272) return;
  int el; u16* dst; int CN; int region;
  if      (e < 16384){ el = e;        dst = pg;  CN = 2; region = 0; }
  else if (e < 32768){ el = e-16384;  dst = pzr; CN = 4; region = 1; }
  else if (e < 40960){ el = e-32768;  dst = pc;  CN = 4; region = 2; }
  else if (e < 45056){ el = e-40960;  dst = pe1; CN = 2; region = 3; }
  else if (e < 49152){ el = e-45056;  dst = pe2; CN = 2; region = 4; }
  else if (e < 53248){ el = e-49152;  dst = pd1; CN = 2; region = 5; }
  else               { el = e-53248;  dst = pav; CN = 2; region = 6; }
  int j    = el & 7;
  int lane = (el >> 3) & 63;
  int rest = el >> 9;
  int c  = rest % CN;
  int ng = rest / CN;
  int k  = c*32 + (lane>>4)*8 + j;
  int n  = ng*16 + (lane&15);
  float val = 0.0f;
  if (region == 0){                 // W_gat [H][64][64], n = hd*64+d
    val = Wg[(size_t)(n>>6)*4096 + k*64 + (n&63)];
  } else if (region == 1){          // [m_perm|h] @ [[Wz Wr],[Uz Ur]]
    int km = (k&3)*16 + ((k>>2)&15);
    if (n < 64) val = (k<64) ? Wz[km*64+n]      : Uz[(k-64)*64+n];
    else        val = (k<64) ? Wr[km*64+(n-64)] : Ur[(k-64)*64+(n-64)];
  } else if (region == 2){          // [m_perm|r*h] @ [[Wc],[Uc]]
    int km = (k&3)*16 + ((k>>2)&15);
    val = (k<64) ? Wc[km*64+n] : Uc[(k-64)*64+n];
  } else if (region == 3){          // W_enc1 [34][64], K padded to 64
    val = (k<34) ? We1[k*64+n] : 0.0f;
  } else if (region == 4){
    val = We2[k*64+n];
  } else if (region == 5){
    val = Wd1[k*64+n];
  } else {                          // pav: 64 x 16, n = 2*hd + s
    int hd = (n>>1)&3, s = n&1;
    const float* av = s ? (adst + hd*64) : (asrc + hd*64);
    const float* wrow = Wg + (size_t)hd*4096 + k*64;
    float acc = 0.f;
    #pragma unroll 8
    for (int d=0; d<64; d++) acc += wrow[d]*av[d];
    val = acc;
  }
  dst[el] = f2bf(val);
}

// ================= shared GEMM helpers =================
template<int CN>
__device__ __forceinline__ void load_b(const u16* p, int chunk, int lane, short8 Bf[CN][4]){
  const short8* P = (const short8*)p;
  #pragma unroll
  for (int c=0;c<CN;c++)
    #pragma unroll
    for (int ng=0; ng<4; ng++)
      Bf[c][ng] = P[((chunk*4+ng)*CN + c)*64 + lane];
}

template<int CN>
__device__ __forceinline__ void mfma_tile(const short8* A, const short8 Bf[CN][4],
                                          floatx4 acc[4][4], int wave, int lane){
  #pragma unroll
  for (int c=0;c<CN;c++){
    #pragma unroll
    for (int mg=0;mg<4;mg++){
      short8 a = A[((wave*4+mg)*CN + c)*64 + lane];
      #pragma unroll
      for (int ng=0;ng<4;ng++)
        acc[mg][ng] = __builtin_amdgcn_mfma_f32_16x16x32_bf16(a, Bf[c][ng], acc[mg][ng], 0, 0, 0);
    }
  }
}

__device__ __forceinline__ void zero_acc(floatx4 acc[4][4]){
  #pragma unroll
  for (int mg=0;mg<4;mg++)
    #pragma unroll
    for (int ng=0;ng<4;ng++){
      floatx4 z = {0.f,0.f,0.f,0.f};
      acc[mg][ng] = z;
    }
}

// ================= encoder (+ cnt zero-init, grid is exactly NN threads) ===========
__global__ __launch_bounds__(128) void k_enc(
    const float* __restrict__ emb, const float* __restrict__ feat,
    const u16* __restrict__ pe1, const u16* __restrict__ pe2,
    const float* __restrict__ be1, const float* __restrict__ be2,
    u16* __restrict__ hout, u32* __restrict__ cnt)
{
  cnt[blockIdx.x*128 + threadIdx.x] = 0u;
  __shared__ short8 A1[1024];
  __shared__ short8 A2[1024];
  const int tid = threadIdx.x;
  const int n0  = blockIdx.x * 128;
  for (int it=0; it<8; ++it){
    int slot = it*128 + tid;
    int row = slot >> 3, jc = slot & 7;
    S8 w;
    if (jc < 4){
      const float* s = emb + (size_t)(n0+row)*32 + jc*8;
      #pragma unroll
      for (int j=0;j<8;j++) w.u[j] = f2bf(s[j]);
    } else if (jc == 4){
      const float* s = feat + (size_t)(n0+row)*2;
      w.u[0] = f2bf(s[0]); w.u[1] = f2bf(s[1]);
      #pragma unroll
      for (int j=2;j<8;j++) w.u[j] = 0;
    } else {
      #pragma unroll
      for (int j=0;j<8;j++) w.u[j] = 0;
    }
    A1[((row>>4)*2 + (jc>>2))*64 + (jc&3)*16 + (row&15)] = w.v;
  }
  __syncthreads();
  const int wave = tid>>6, lane = tid&63, q = lane>>4, ml = lane&15;

  short8 Bf[2][4];
  load_b<2>(pe1, 0, lane, Bf);
  floatx4 acc[4][4];
  zero_acc(acc);
  mfma_tile<2>(A1, Bf, acc, wave, lane);

  u16* A2s = (u16*)A2;
  #pragma unroll
  for (int mg=0;mg<4;mg++){
    #pragma unroll
    for (int r=0;r<4;r++){
      int row_l = wave*64 + mg*16 + q*4 + r;
      #pragma unroll
      for (int ng=0;ng<4;ng++){
        int k2 = ng*16 + ml;
        float v = tanhf(acc[mg][ng][r] + be1[k2]);
        int c2 = k2>>5, q2=(k2>>3)&3, j2=k2&7;
        A2s[ (((row_l>>4)*2 + c2)*64 + q2*16 + (row_l&15))*8 + j2 ] = f2bf(v);
      }
    }
  }
  __syncthreads();

  load_b<2>(pe2, 0, lane, Bf);
  zero_acc(acc);
  mfma_tile<2>(A2, Bf, acc, wave, lane);
  #pragma unroll
  for (int mg=0;mg<4;mg++)
    #pragma unroll
    for (int r=0;r<4;r++){
      int row = n0 + wave*64 + mg*16 + q*4 + r;
      #pragma unroll
      for (int ng=0;ng<4;ng++){
        int col = ng*16 + ml;
        hout[(size_t)row*64 + col] = f2bf(tanhf(acc[mg][ng][r] + be2[col]));
      }
    }
}

// ===== t = h @ W_gat (4 heads) -> fp8 rows (permuted) + scores via MFMA =====
__global__ __launch_bounds__(128) void k_t(
    const u16* __restrict__ h, const u16* __restrict__ pg, const u16* __restrict__ pav,
    u32* __restrict__ tq, float* __restrict__ ss)
{
  __shared__ short8 A[1024];
  const int tid = threadIdx.x;
  const int n0  = blockIdx.x * 128;
  const short8* hp = (const short8*)h;
  for (int it=0; it<8; ++it){
    int slot = it*128 + tid;
    int row = slot >> 3, jc = slot & 7;
    A[((row>>4)*2 + (jc>>2))*64 + (jc&3)*16 + (row&15)] = hp[(size_t)(n0+row)*8 + jc];
  }
  __syncthreads();
  const int wave = tid>>6, lane = tid&63, q = lane>>4, ml = lane&15;

  for (int chunk=0; chunk<4; ++chunk){       // chunk == head
    short8 Bf[2][4];
    load_b<2>(pg, chunk, lane, Bf);
    floatx4 acc[4][4];
    zero_acc(acc);
    mfma_tile<2>(A, Bf, acc, wave, lane);

    #pragma unroll
    for (int mg=0;mg<4;mg++){
      #pragma unroll
      for (int r=0;r<4;r++){
        int row = n0 + wave*64 + mg*16 + q*4 + r;
        int pk = __builtin_amdgcn_cvt_pk_fp8_f32(acc[mg][0][r], acc[mg][1][r], 0, false);
        pk     = __builtin_amdgcn_cvt_pk_fp8_f32(acc[mg][2][r], acc[mg][3][r], pk, true);
        tq[(size_t)row*64 + chunk*16 + ml] = (u32)pk;
      }
    }
  }

  // scores: [h] @ pav (64x16); lanes ml<8 hold the 8 scores per row
  const short8* Pv = (const short8*)pav;
  short8 Bs0 = Pv[lane], Bs1 = Pv[64 + lane];
  #pragma unroll
  for (int mg=0;mg<4;mg++){
    floatx4 sacc = {0.f,0.f,0.f,0.f};
    short8 a0 = A[((wave*4+mg)*2 + 0)*64 + lane];
    short8 a1 = A[((wave*4+mg)*2 + 1)*64 + lane];
    sacc = __builtin_amdgcn_mfma_f32_16x16x32_bf16(a0, Bs0, sacc, 0, 0, 0);
    sacc = __builtin_amdgcn_mfma_f32_16x16x32_bf16(a1, Bs1, sacc, 0, 0, 0);
    if (ml < 8){
      #pragma unroll
      for (int r=0;r<4;r++){
        int row = n0 + wave*64 + mg*16 + q*4 + r;
        ss[(size_t)row*8 + ml] = sacc[r];
      }
    }
  }
}

// ====== attention + aggregate + tanh(m); XCD batch-affinity swizzle ======
__global__ __launch_bounds__(256) void k_attn(
    const int* __restrict__ adj, const u32* __restrict__ tq,
    const float* __restrict__ ss, u16* __restrict__ m)
{
  const int wave = threadIdx.x>>6, lane = threadIdx.x&63;
  const int bid = blockIdx.x;
  const int b   = (bid & 7) >> 1;                    // batch from XCD
  const int loc = (bid >> 3)*2 + (bid & 1);          // 0..4095 within batch
  const int nid = b*VN + loc*4 + wave;
  const int hd = lane>>4;
  int u = adj[(size_t)nid*16 + (lane&15)];
  float sc = (u == VN) ? NEGC : (ss[(size_t)nid*8 + hd*2] + ss[((size_t)b*VN + u)*8 + hd*2 + 1]);
  float mx = sc;
  #pragma unroll
  for (int s=1;s<16;s<<=1) mx = fmaxf(mx, __shfl_xor(mx, s, 64));
  float ex = expf(sc - mx);
  float sm = ex;
  #pragma unroll
  for (int s=1;s<16;s<<=1) sm += __shfl_xor(sm, s, 64);
  float attn = ex / sm;

  float a0=0.f, a1=0.f, a2=0.f, a3=0.f;
  const int srcl = lane & 48;
  #pragma unroll
  for (int k2=0;k2<16;k2++){
    int u2 = __shfl(u, k2, 64);             // wave-uniform
    float av = __shfl(attn, srcl + k2, 64);
    u32 w = tq[((size_t)b*VN + u2)*64 + lane];
    floatx2 f01 = __builtin_amdgcn_cvt_pk_f32_fp8((int)w, false);
    floatx2 f23 = __builtin_amdgcn_cvt_pk_f32_fp8((int)w, true);
    a0 += av*f01.x; a1 += av*f01.y; a2 += av*f23.x; a3 += av*f23.y;
  }
  a0 += __shfl_xor(a0,16,64); a0 += __shfl_xor(a0,32,64);
  a1 += __shfl_xor(a1,16,64); a1 += __shfl_xor(a1,32,64);
  a2 += __shfl_xor(a2,16,64); a2 += __shfl_xor(a2,32,64);
  a3 += __shfl_xor(a3,16,64); a3 += __shfl_xor(a3,32,64);
  if (lane < 16){
    union { uint2 v; u16 u[4]; } val;
    val.u[0] = f2bf(tanhf(a0*0.25f)); val.u[1] = f2bf(tanhf(a1*0.25f));
    val.u[2] = f2bf(tanhf(a2*0.25f)); val.u[3] = f2bf(tanhf(a3*0.25f));
    *(uint2*)(m + (size_t)nid*64 + lane*4) = val.v;
  }
}

// ====== fused GRU (h, m bf16); optional fused DECODER on last layer ======
__global__ __launch_bounds__(128) void k_gru(
    const u16* __restrict__ m, u16* __restrict__ h,
    const u16* __restrict__ pzr, const u16* __restrict__ pc_,
    const float* __restrict__ bz, const float* __restrict__ br,
    const float* __restrict__ bc_,
    const u16* __restrict__ pd1, const float* __restrict__ bd1,
    const float* __restrict__ Wd2, const float* __restrict__ bd2,
    float* __restrict__ nodew)
{
  __shared__ short8 A[2048];
  const int tid = threadIdx.x;
  const int n0  = blockIdx.x * 128;
  const short8* mp = (const short8*)m;
  const short8* hp = (const short8*)h;
  for (int it=0; it<16; ++it){
    int slot = it*128 + tid;
    int row = slot >> 4, jc = slot & 15;
    short8 w = (jc < 8) ? mp[(size_t)(n0+row)*8 + jc]
                        : hp[(size_t)(n0+row)*8 + (jc-8)];
    A[((row>>4)*4 + (jc>>2))*64 + (jc&3)*16 + (row&15)] = w;
  }
  __syncthreads();
  const int wave = tid>>6, lane = tid&63, q = lane>>4, ml = lane&15;

  short8 Bf[4][4];

  floatx4 zacc[4][4];
  load_b<4>(pzr, 0, lane, Bf);
  zero_acc(zacc);
  mfma_tile<4>(A, Bf, zacc, wave, lane);

  floatx4 acc[4][4];
  load_b<4>(pzr, 1, lane, Bf);
  zero_acc(acc);
  mfma_tile<4>(A, Bf, acc, wave, lane);

  floatx4 h_old[4][4];
  u16* As = (u16*)A;
  #pragma unroll
  for (int mg=0;mg<4;mg++){
    #pragma unroll
    for (int r=0;r<4;r++){
      int row_l = wave*64 + mg*16 + q*4 + r;
      int row   = n0 + row_l;
      #pragma unroll
      for (int ng=0;ng<4;ng++){
        int col = ng*16 + ml;
        float rv = sigm(acc[mg][ng][r] + br[col]);
        float hv = bf2f(h[(size_t)row*64 + col]);
        h_old[mg][ng][r] = hv;
        int kk = 64 + col;
        int c2 = kk>>5, q2 = (kk>>3)&3, j2 = kk&7;
        As[ (((row_l>>4)*4 + c2)*64 + q2*16 + (row_l&15))*8 + j2 ] = f2bf(hv*rv);
      }
    }
  }
  // no __syncthreads: wave-local rows only (lgkmcnt orders LDS ops).

  load_b<4>(pc_, 0, lane, Bf);
  zero_acc(acc);
  mfma_tile<4>(A, Bf, acc, wave, lane);

  #pragma unroll
  for (int mg=0;mg<4;mg++)
    #pragma unroll
    for (int r=0;r<4;r++){
      int row_l = wave*64 + mg*16 + q*4 + r;
      int row   = n0 + row_l;
      #pragma unroll
      for (int ng=0;ng<4;ng++){
        int col = ng*16 + ml;
        float zv = sigm(zacc[mg][ng][r] + bz[col]);
        float cv = tanhf(acc[mg][ng][r] + bc_[col]);
        float ho = h_old[mg][ng][r];
        float hn = (1.f - zv)*ho + zv*cv;
        if (nodew == nullptr){
          h[(size_t)row*64 + col] = f2bf(hn);
        } else {
          int kk = 64 + col;
          int c2 = kk>>5, q2 = (kk>>3)&3, j2 = kk&7;
          As[ (((row_l>>4)*4 + c2)*64 + q2*16 + (row_l&15))*8 + j2 ] = f2bf(hn);
        }
      }
    }

  if (nodew){
    short8 Bd[2][4];
    load_b<2>(pd1, 0, lane, Bd);
    floatx4 dacc[4][4];
    zero_acc(dacc);
    #pragma unroll
    for (int c=0;c<2;c++){
      #pragma unroll
      for (int mg=0;mg<4;mg++){
        short8 a = A[((wave*4+mg)*4 + (2+c))*64 + lane];
        #pragma unroll
        for (int ng=0;ng<4;ng++)
          dacc[mg][ng] = __builtin_amdgcn_mfma_f32_16x16x32_bf16(a, Bd[c][ng], dacc[mg][ng], 0, 0, 0);
      }
    }
    float wd2l[4];
    #pragma unroll
    for (int ng=0;ng<4;ng++) wd2l[ng] = Wd2[ng*16 + ml];
    float b2 = bd2[0];
    #pragma unroll
    for (int mg=0;mg<4;mg++)
      #pragma unroll
      for (int r=0;r<4;r++){
        int row = n0 + wave*64 + mg*16 + q*4 + r;
        float ps = 0.f;
        #pragma unroll
        for (int ng=0;ng<4;ng++)
          ps += tanhf(dacc[mg][ng][r] + bd1[ng*16+ml]) * wd2l[ng];
        #pragma unroll
        for (int s=1;s<16;s<<=1) ps += __shfl_xor(ps, s, 64);
        if (ml == 0) nodew[row] = ps + b2;
      }
  }
}

// ========== COOPERATIVE solver: softmax+bucket build, then 10 gathers ==========
// 1024 blocks x 256 threads = 4 blocks/CU co-resident. Each block owns 64 nodes
// (XCD batch-affinity: bid&7 -> XCD, XCD pair serves one batch). grid.sync()
// separates phases; flow/pflow/cost fused into iters 9/10.
__global__ __launch_bounds__(256) void k_solver(
    const int* __restrict__ adj, const float* __restrict__ nodew, const float* __restrict__ dem,
    float* __restrict__ normw, u32* __restrict__ cnt, u32* __restrict__ bucket,
    float* __restrict__ nv0b, float* __restrict__ nv1b,
    float* __restrict__ flow, float* __restrict__ pflow, float* __restrict__ cost)
{
  cg::grid_group grid = cg::this_grid();
  const int bid = blockIdx.x;
  const int b   = (bid & 7) >> 1;                    // batch from XCD
  const int loc = (bid >> 3)*2 + (bid & 1);          // 0..255 within batch
  const int tid = threadIdx.x;
  const int lane16 = tid & 15;
  const int g0 = b*VN + loc*64;                      // this block's 64 nodes

  if (bid == 0 && tid < BN) cost[tid] = 0.f;

  // ---- Phase A: softmax + nv0 + atomic bucket build (1024 edges/block) ----
  #pragma unroll
  for (int sub=0; sub<4; ++sub){
    int node = g0 + sub*16 + (tid>>4);
    int e = node*16 + lane16;
    int u = adj[e];
    float pw = (u == VN) ? NEGC : nodew[(size_t)b*VN + u];
    float mx = pw;
    #pragma unroll
    for (int s=1;s<16;s<<=1) mx = fmaxf(mx, __shfl_xor(mx, s, 64));
    float ex = expf(pw - mx);
    float sm = ex;
    #pragma unroll
    for (int s=1;s<16;s<<=1) sm += __shfl_xor(sm, s, 64);
    float nw = ex / sm;
    normw[e] = nw;
    if (lane16 == 0) nv0b[node] = fmaxf(-dem[node], 0.f);
    if (u < VN){
      int g = b*VN + u;
      u32 pos = atomicAdd(&cnt[g], 1u);
      if (pos < CAP)
        bucket[(size_t)g*CAP + pos] = ((u32)f2bf(nw) << 16) | (u32)(node & (VN-1));
    }
  }
  grid.sync();

  // ---- Phase B: 10 gather iterations with grid-wide sync between ----
  for (int it=1; it<=10; ++it){
    const float* nin = (it & 1) ? nv0b : nv1b;
    float* nout      = (it & 1) ? nv1b : nv0b;
    float* fo = (it==10) ? flow : ((it==9) ? pflow : nullptr);
    float csum = 0.f;
    #pragma unroll
    for (int sub=0; sub<4; ++sub){
      int g = g0 + sub*16 + (tid>>4);
      u32 n = cnt[g];
      if (n > CAP) n = CAP;
      const u32* bk = bucket + (size_t)g*CAP;
      const float* nb = nin + (size_t)b*VN;
      float sum = 0.f;
      for (u32 i = (u32)lane16; i < n; i += 16u){
        u32 r = bk[i];
        sum += bf2f(r >> 16) * nb[r & 0xFFFFu];
      }
      #pragma unroll
      for (int sh=1; sh<16; sh<<=1) sum += __shfl_xor(sum, sh, 64);
      float nvv = fmaxf(sum - dem[g], 0.f);
      if (lane16 == 0) nout[g] = nvv;
      if (fo){
        int e = g*16 + lane16;
        float fl = normw[e] * nvv;
        fo[e] = fl;
        if (it == 10) csum += fl*fl;
      }
    }
    if (it == 10){
      #pragma unroll
      for (int sh=1; sh<64; sh<<=1) csum += __shfl_xor(csum, sh, 64);
      __shared__ float part[4];
      if ((tid & 63) == 0) part[tid>>6] = csum;
      __syncthreads();
      if (tid == 0) atomicAdd(cost + b, part[0]+part[1]+part[2]+part[3]);
    }
    grid.sync();
  }
}

// ================= launcher =================
extern "C" void kernel_launch(void* const* d_in, const int* in_sizes, int n_in,
                              void* d_out, int out_size, void* d_ws, size_t ws_size,
                              hipStream_t stream)
{
  const float* emb  = (const float*)d_in[0];
  const float* feat = (const float*)d_in[1];
  const float* dem  = (const float*)d_in[2];
  const int*   adj  = (const int*)  d_in[3];
  const float* We1 = (const float*)d_in[6];
  const float* be1 = (const float*)d_in[7];
  const float* We2 = (const float*)d_in[8];
  const float* be2 = (const float*)d_in[9];
  const float* Wg  = (const float*)d_in[10];
  const float* asrc= (const float*)d_in[11];
  const float* adst= (const float*)d_in[12];
  const float* Wz  = (const float*)d_in[13];
  const float* Uz  = (const float*)d_in[14];
  const float* bz  = (const float*)d_in[15];
  const float* Wr  = (const float*)d_in[16];
  const float* Ur  = (const float*)d_in[17];
  const float* br  = (const float*)d_in[18];
  const float* Wc  = (const float*)d_in[19];
  const float* Uc  = (const float*)d_in[20];
  const float* bc  = (const float*)d_in[21];
  const float* Wd1 = (const float*)d_in[22];
  const float* bd1 = (const float*)d_in[23];
  const float* Wd2 = (const float*)d_in[24];
  const float* bd2 = (const float*)d_in[25];

  char* ws = (char*)d_ws;
  u16*   h     = (u16*)  (ws + OFF_H);
  u16*   m     = (u16*)  (ws + OFF_M);
  u32*   tq    = (u32*)  (ws + OFF_T);          // fp8 t-table, [NN+1][64] u32
  u32*   bucket= (u32*)  (ws + OFF_T);          // overlays t after attn done
  float* ss    = (float*)(ws + OFF_SS);
  float* nodew = (float*)(ws + OFF_NW);
  float* nv    = (float*)(ws + OFF_NV);         // [2][NN]
  u32*   cnt   = (u32*)  (ws + OFF_CNT);
  u16* pg  = (u16*)(ws + OFF_PG);
  u16* pzr = (u16*)(ws + OFF_PZR);
  u16* pc  = (u16*)(ws + OFF_PC);
  u16* pe1 = (u16*)(ws + OFF_PE1);
  u16* pe2 = (u16*)(ws + OFF_PE2);
  u16* pd1 = (u16*)(ws + OFF_PD1);
  u16* pav = (u16*)(ws + OFF_PAV);
  float* nv0b = nv;
  float* nv1b = nv + NN;

  float* out0 = (float*)d_out;            // flow   [B,V,K]  (= f10)
  float* out1 = out0 + 1048576;           // flow_cost [B]
  float* out2 = out0 + 1048580;           // norm_w [B,V,K]
  float* out3 = out0 + 2097156;           // pflow  [B,V,K]  (= f9)

  k_pack<<<212, 256, 0, stream>>>(Wg, Wz, Uz, Wr, Ur, Wc, Uc, We1, We2, Wd1,
                                  asrc, adst, pg, pzr, pc, pe1, pe2, pd1, pav);
  k_enc<<<512, 128, 0, stream>>>(emb, feat, pe1, pe2, be1, be2, h, cnt);

  for (int l=0; l<2; ++l){
    k_t   <<<512, 128, 0, stream>>>(h, pg, pav, tq, ss);
    k_attn<<<16384, 256, 0, stream>>>(adj, tq, ss, m);
    k_gru <<<512, 128, 0, stream>>>(m, h, pzr, pc, bz, br, bc,
                                    pd1, bd1, Wd2, bd2, (l==1) ? nodew : nullptr);
  }

  // cooperative solver: bucket build + 10 gather iterations, one launch
  {
    const int*   a_adj   = adj;
    const float* a_nodew = nodew;
    const float* a_dem   = dem;
    float* a_normw = out2;
    u32*   a_cnt   = cnt;
    u32*   a_bkt   = bucket;
    float* a_nv0   = nv0b;
    float* a_nv1   = nv1b;
    float* a_flow  = out0;
    float* a_pflow = out3;
    float* a_cost  = out1;
    void* kargs[] = { (void*)&a_adj, (void*)&a_nodew, (void*)&a_dem,
                      (void*)&a_normw, (void*)&a_cnt, (void*)&a_bkt,
                      (void*)&a_nv0, (void*)&a_nv1,
                      (void*)&a_flow, (void*)&a_pflow, (void*)&a_cost };
    hipLaunchCooperativeKernel((void*)k_solver, dim3(1024), dim3(256),
                               kargs, 0, stream);
  }
}

// Round 12
// 444.276 us; speedup vs baseline: 3.6810x; 3.6810x over previous
//
#include <hip/hip_runtime.h>
#include <stdint.h>
#include <math.h>

// Problem constants
#define BN 4
#define VN 16384
#define KN 16
#define HN 4
#define NN (BN*VN)          // 65536 nodes total
#define EN (VN*KN)          // 262144 edges per batch
#define CAP 64              // inverse-adjacency bucket capacity (P(deg>64) ~ 1e-13)
#define NEGC (-1.0e9f)

typedef __attribute__((ext_vector_type(8))) short short8;
typedef __attribute__((ext_vector_type(4))) float floatx4;
typedef __attribute__((ext_vector_type(2))) float floatx2;
typedef unsigned short u16;
typedef unsigned int u32;

// ---------- workspace layout (bytes) ----------
#define OFF_H      0ull                     // h       bf16 [NN][64]    8 MB
#define OFF_M      8388608ull               // m       bf16 [NN][64]    8 MB (PERMUTED dim order)
#define OFF_T      16777216ull              // t_all fp8 u32[NN+1][64] 16.8 MB; REUSED as bucket u32[NN][64] (16MB)
#define OFF_SS     50331648ull              // ss      fp32 [NN][8]     2 MB (scores: [2hd+0]=src, [2hd+1]=dst)
#define OFF_NW     52428800ull              // node_w  fp32 [NN]      256 KB
#define OFF_NV     52690944ull              // nv      fp32 [2][NN]   512 KB
#define OFF_CNT    53215232ull              // cnt     u32  [NN]      256 KB
#define OFF_PG     53477376ull              // packed W_gat   32 KB
#define OFF_PZR    (OFF_PG  + 32768ull)     // packed Wz|Wr/Uz|Ur 32 KB
#define OFF_PC     (OFF_PZR + 32768ull)     // packed Wc/Uc   16 KB
#define OFF_PE1    (OFF_PC  + 16384ull)     // packed W_enc1 (K padded to 64) 8 KB
#define OFF_PE2    (OFF_PE1 + 8192ull)      // packed W_enc2  8 KB
#define OFF_PD1    (OFF_PE2 + 8192ull)      // packed W_dec1  8 KB
#define OFF_PAV    (OFF_PD1 + 8192ull)      // packed W_gat@a_{src,dst} 64x16  2 KB
// total ws use ~53.6 MB

__device__ __forceinline__ u16 f2bf(float x){
  union { float f; unsigned int u; } c; c.f = x;
  unsigned int r = c.u + 0x7fffu + ((c.u >> 16) & 1u);
  return (u16)(r >> 16);
}
__device__ __forceinline__ float bf2f(u32 s){
  union { unsigned int u; float f; } c; c.u = s << 16;
  return c.f;
}
__device__ __forceinline__ float sigm(float x){ return 1.0f/(1.0f+expf(-x)); }

union S8 { short8 v; u16 u[8]; };

// ================= weight pack kernel =================
// packed layout: flat elem e = ((ng*CN + c)*64 + lane)*8 + j holds Mat[k][n],
// k = c*32 + (lane>>4)*8 + j,  n = ng*16 + (lane&15),  CN = K/32.
// m is PERMUTED: m_perm[p] = m_std[(p&3)*16 + (p>>2)] -> un-permute its rows here.
// region 6 (pav): M[k][2hd+s] = sum_n W_gat[hd][k][n] * a_{s}[hd][n]
__global__ __launch_bounds__(256) void k_pack(
    const float* __restrict__ Wg,  const float* __restrict__ Wz, const float* __restrict__ Uz,
    const float* __restrict__ Wr,  const float* __restrict__ Ur, const float* __restrict__ Wc,
    const float* __restrict__ Uc,  const float* __restrict__ We1, const float* __restrict__ We2,
    const float* __restrict__ Wd1, const float* __restrict__ asrc, const float* __restrict__ adst,
    u16* __restrict__ pg, u16* __restrict__ pzr, u16* __restrict__ pc,
    u16* __restrict__ pe1, u16* __restrict__ pe2, u16* __restrict__ pd1,
    u16* __restrict__ pav)
{
  int e = blockIdx.x*256 + threadIdx.x;   // 0 .. 54271
  if (e >= 54272) return;
  int el; u16* dst; int CN; int region;
  if      (e < 16384){ el = e;        dst = pg;  CN = 2; region = 0; }
  else if (e < 32768){ el = e-16384;  dst = pzr; CN = 4; region = 1; }
  else if (e < 40960){ el = e-32768;  dst = pc;  CN = 4; region = 2; }
  else if (e < 45056){ el = e-40960;  dst = pe1; CN = 2; region = 3; }
  else if (e < 49152){ el = e-45056;  dst = pe2; CN = 2; region = 4; }
  else if (e < 53248){ el = e-49152;  dst = pd1; CN = 2; region = 5; }
  else               { el = e-53248;  dst = pav; CN = 2; region = 6; }
  int j    = el & 7;
  int lane = (el >> 3) & 63;
  int rest = el >> 9;
  int c  = rest % CN;
  int ng = rest / CN;
  int k  = c*32 + (lane>>4)*8 + j;
  int n  = ng*16 + (lane&15);
  float val = 0.0f;
  if (region == 0){                 // W_gat [H][64][64], n = hd*64+d
    val = Wg[(size_t)(n>>6)*4096 + k*64 + (n&63)];
  } else if (region == 1){          // [m_perm|h] @ [[Wz Wr],[Uz Ur]]
    int km = (k&3)*16 + ((k>>2)&15);
    if (n < 64) val = (k<64) ? Wz[km*64+n]      : Uz[(k-64)*64+n];
    else        val = (k<64) ? Wr[km*64+(n-64)] : Ur[(k-64)*64+(n-64)];
  } else if (region == 2){          // [m_perm|r*h] @ [[Wc],[Uc]]
    int km = (k&3)*16 + ((k>>2)&15);
    val = (k<64) ? Wc[km*64+n] : Uc[(k-64)*64+n];
  } else if (region == 3){          // W_enc1 [34][64], K padded to 64
    val = (k<34) ? We1[k*64+n] : 0.0f;
  } else if (region == 4){
    val = We2[k*64+n];
  } else if (region == 5){
    val = Wd1[k*64+n];
  } else {                          // pav: 64 x 16, n = 2*hd + s
    int hd = (n>>1)&3, s = n&1;
    const float* av = s ? (adst + hd*64) : (asrc + hd*64);
    const float* wrow = Wg + (size_t)hd*4096 + k*64;
    float acc = 0.f;
    #pragma unroll 8
    for (int d=0; d<64; d++) acc += wrow[d]*av[d];
    val = acc;
  }
  dst[el] = f2bf(val);
}

// ================= shared GEMM helpers =================
template<int CN>
__device__ __forceinline__ void load_b(const u16* p, int chunk, int lane, short8 Bf[CN][4]){
  const short8* P = (const short8*)p;
  #pragma unroll
  for (int c=0;c<CN;c++)
    #pragma unroll
    for (int ng=0; ng<4; ng++)
      Bf[c][ng] = P[((chunk*4+ng)*CN + c)*64 + lane];
}

template<int CN>
__device__ __forceinline__ void mfma_tile(const short8* A, const short8 Bf[CN][4],
                                          floatx4 acc[4][4], int wave, int lane){
  #pragma unroll
  for (int c=0;c<CN;c++){
    #pragma unroll
    for (int mg=0;mg<4;mg++){
      short8 a = A[((wave*4+mg)*CN + c)*64 + lane];
      #pragma unroll
      for (int ng=0;ng<4;ng++)
        acc[mg][ng] = __builtin_amdgcn_mfma_f32_16x16x32_bf16(a, Bf[c][ng], acc[mg][ng], 0, 0, 0);
    }
  }
}

__device__ __forceinline__ void zero_acc(floatx4 acc[4][4]){
  #pragma unroll
  for (int mg=0;mg<4;mg++)
    #pragma unroll
    for (int ng=0;ng<4;ng++){
      floatx4 z = {0.f,0.f,0.f,0.f};
      acc[mg][ng] = z;
    }
}

// ================= encoder (+ cnt zero-init, grid is exactly NN threads) ===========
__global__ __launch_bounds__(128) void k_enc(
    const float* __restrict__ emb, const float* __restrict__ feat,
    const u16* __restrict__ pe1, const u16* __restrict__ pe2,
    const float* __restrict__ be1, const float* __restrict__ be2,
    u16* __restrict__ hout, u32* __restrict__ cnt)
{
  cnt[blockIdx.x*128 + threadIdx.x] = 0u;
  __shared__ short8 A1[1024];
  __shared__ short8 A2[1024];
  const int tid = threadIdx.x;
  const int n0  = blockIdx.x * 128;
  for (int it=0; it<8; ++it){
    int slot = it*128 + tid;
    int row = slot >> 3, jc = slot & 7;
    S8 w;
    if (jc < 4){
      const float* s = emb + (size_t)(n0+row)*32 + jc*8;
      #pragma unroll
      for (int j=0;j<8;j++) w.u[j] = f2bf(s[j]);
    } else if (jc == 4){
      const float* s = feat + (size_t)(n0+row)*2;
      w.u[0] = f2bf(s[0]); w.u[1] = f2bf(s[1]);
      #pragma unroll
      for (int j=2;j<8;j++) w.u[j] = 0;
    } else {
      #pragma unroll
      for (int j=0;j<8;j++) w.u[j] = 0;
    }
    A1[((row>>4)*2 + (jc>>2))*64 + (jc&3)*16 + (row&15)] = w.v;
  }
  __syncthreads();
  const int wave = tid>>6, lane = tid&63, q = lane>>4, ml = lane&15;

  short8 Bf[2][4];
  load_b<2>(pe1, 0, lane, Bf);
  floatx4 acc[4][4];
  zero_acc(acc);
  mfma_tile<2>(A1, Bf, acc, wave, lane);

  u16* A2s = (u16*)A2;
  #pragma unroll
  for (int mg=0;mg<4;mg++){
    #pragma unroll
    for (int r=0;r<4;r++){
      int row_l = wave*64 + mg*16 + q*4 + r;
      #pragma unroll
      for (int ng=0;ng<4;ng++){
        int k2 = ng*16 + ml;
        float v = tanhf(acc[mg][ng][r] + be1[k2]);
        int c2 = k2>>5, q2=(k2>>3)&3, j2=k2&7;
        A2s[ (((row_l>>4)*2 + c2)*64 + q2*16 + (row_l&15))*8 + j2 ] = f2bf(v);
      }
    }
  }
  __syncthreads();

  load_b<2>(pe2, 0, lane, Bf);
  zero_acc(acc);
  mfma_tile<2>(A2, Bf, acc, wave, lane);
  #pragma unroll
  for (int mg=0;mg<4;mg++)
    #pragma unroll
    for (int r=0;r<4;r++){
      int row = n0 + wave*64 + mg*16 + q*4 + r;
      #pragma unroll
      for (int ng=0;ng<4;ng++){
        int col = ng*16 + ml;
        hout[(size_t)row*64 + col] = f2bf(tanhf(acc[mg][ng][r] + be2[col]));
      }
    }
}

// ===== t = h @ W_gat (4 heads) -> fp8 rows (permuted) + scores via MFMA =====
__global__ __launch_bounds__(128) void k_t(
    const u16* __restrict__ h, const u16* __restrict__ pg, const u16* __restrict__ pav,
    u32* __restrict__ tq, float* __restrict__ ss)
{
  __shared__ short8 A[1024];
  const int tid = threadIdx.x;
  const int n0  = blockIdx.x * 128;
  const short8* hp = (const short8*)h;
  for (int it=0; it<8; ++it){
    int slot = it*128 + tid;
    int row = slot >> 3, jc = slot & 7;
    A[((row>>4)*2 + (jc>>2))*64 + (jc&3)*16 + (row&15)] = hp[(size_t)(n0+row)*8 + jc];
  }
  __syncthreads();
  const int wave = tid>>6, lane = tid&63, q = lane>>4, ml = lane&15;

  for (int chunk=0; chunk<4; ++chunk){       // chunk == head
    short8 Bf[2][4];
    load_b<2>(pg, chunk, lane, Bf);
    floatx4 acc[4][4];
    zero_acc(acc);
    mfma_tile<2>(A, Bf, acc, wave, lane);

    #pragma unroll
    for (int mg=0;mg<4;mg++){
      #pragma unroll
      for (int r=0;r<4;r++){
        int row = n0 + wave*64 + mg*16 + q*4 + r;
        int pk = __builtin_amdgcn_cvt_pk_fp8_f32(acc[mg][0][r], acc[mg][1][r], 0, false);
        pk     = __builtin_amdgcn_cvt_pk_fp8_f32(acc[mg][2][r], acc[mg][3][r], pk, true);
        tq[(size_t)row*64 + chunk*16 + ml] = (u32)pk;
      }
    }
  }

  // scores: [h] @ pav (64x16); lanes ml<8 hold the 8 scores per row
  const short8* Pv = (const short8*)pav;
  short8 Bs0 = Pv[lane], Bs1 = Pv[64 + lane];
  #pragma unroll
  for (int mg=0;mg<4;mg++){
    floatx4 sacc = {0.f,0.f,0.f,0.f};
    short8 a0 = A[((wave*4+mg)*2 + 0)*64 + lane];
    short8 a1 = A[((wave*4+mg)*2 + 1)*64 + lane];
    sacc = __builtin_amdgcn_mfma_f32_16x16x32_bf16(a0, Bs0, sacc, 0, 0, 0);
    sacc = __builtin_amdgcn_mfma_f32_16x16x32_bf16(a1, Bs1, sacc, 0, 0, 0);
    if (ml < 8){
      #pragma unroll
      for (int r=0;r<4;r++){
        int row = n0 + wave*64 + mg*16 + q*4 + r;
        ss[(size_t)row*8 + ml] = sacc[r];
      }
    }
  }
}

// ====== attention + aggregate + tanh(m); XCD batch-affinity swizzle ======
__global__ __launch_bounds__(256) void k_attn(
    const int* __restrict__ adj, const u32* __restrict__ tq,
    const float* __restrict__ ss, u16* __restrict__ m)
{
  const int wave = threadIdx.x>>6, lane = threadIdx.x&63;
  const int bid = blockIdx.x;
  const int b   = (bid & 7) >> 1;                    // batch from XCD
  const int loc = (bid >> 3)*2 + (bid & 1);          // 0..4095 within batch
  const int nid = b*VN + loc*4 + wave;
  const int hd = lane>>4;
  int u = adj[(size_t)nid*16 + (lane&15)];
  float sc = (u == VN) ? NEGC : (ss[(size_t)nid*8 + hd*2] + ss[((size_t)b*VN + u)*8 + hd*2 + 1]);
  float mx = sc;
  #pragma unroll
  for (int s=1;s<16;s<<=1) mx = fmaxf(mx, __shfl_xor(mx, s, 64));
  float ex = expf(sc - mx);
  float sm = ex;
  #pragma unroll
  for (int s=1;s<16;s<<=1) sm += __shfl_xor(sm, s, 64);
  float attn = ex / sm;

  float a0=0.f, a1=0.f, a2=0.f, a3=0.f;
  const int srcl = lane & 48;
  #pragma unroll
  for (int k2=0;k2<16;k2++){
    int u2 = __shfl(u, k2, 64);             // wave-uniform
    float av = __shfl(attn, srcl + k2, 64);
    u32 w = tq[((size_t)b*VN + u2)*64 + lane];
    floatx2 f01 = __builtin_amdgcn_cvt_pk_f32_fp8((int)w, false);
    floatx2 f23 = __builtin_amdgcn_cvt_pk_f32_fp8((int)w, true);
    a0 += av*f01.x; a1 += av*f01.y; a2 += av*f23.x; a3 += av*f23.y;
  }
  a0 += __shfl_xor(a0,16,64); a0 += __shfl_xor(a0,32,64);
  a1 += __shfl_xor(a1,16,64); a1 += __shfl_xor(a1,32,64);
  a2 += __shfl_xor(a2,16,64); a2 += __shfl_xor(a2,32,64);
  a3 += __shfl_xor(a3,16,64); a3 += __shfl_xor(a3,32,64);
  if (lane < 16){
    union { uint2 v; u16 u[4]; } val;
    val.u[0] = f2bf(tanhf(a0*0.25f)); val.u[1] = f2bf(tanhf(a1*0.25f));
    val.u[2] = f2bf(tanhf(a2*0.25f)); val.u[3] = f2bf(tanhf(a3*0.25f));
    *(uint2*)(m + (size_t)nid*64 + lane*4) = val.v;
  }
}

// ====== fused GRU (h, m bf16); optional fused DECODER on last layer ======
__global__ __launch_bounds__(128) void k_gru(
    const u16* __restrict__ m, u16* __restrict__ h,
    const u16* __restrict__ pzr, const u16* __restrict__ pc_,
    const float* __restrict__ bz, const float* __restrict__ br,
    const float* __restrict__ bc_,
    const u16* __restrict__ pd1, const float* __restrict__ bd1,
    const float* __restrict__ Wd2, const float* __restrict__ bd2,
    float* __restrict__ nodew)
{
  __shared__ short8 A[2048];
  const int tid = threadIdx.x;
  const int n0  = blockIdx.x * 128;
  const short8* mp = (const short8*)m;
  const short8* hp = (const short8*)h;
  for (int it=0; it<16; ++it){
    int slot = it*128 + tid;
    int row = slot >> 4, jc = slot & 15;
    short8 w = (jc < 8) ? mp[(size_t)(n0+row)*8 + jc]
                        : hp[(size_t)(n0+row)*8 + (jc-8)];
    A[((row>>4)*4 + (jc>>2))*64 + (jc&3)*16 + (row&15)] = w;
  }
  __syncthreads();
  const int wave = tid>>6, lane = tid&63, q = lane>>4, ml = lane&15;

  short8 Bf[4][4];

  floatx4 zacc[4][4];
  load_b<4>(pzr, 0, lane, Bf);
  zero_acc(zacc);
  mfma_tile<4>(A, Bf, zacc, wave, lane);

  floatx4 acc[4][4];
  load_b<4>(pzr, 1, lane, Bf);
  zero_acc(acc);
  mfma_tile<4>(A, Bf, acc, wave, lane);

  floatx4 h_old[4][4];
  u16* As = (u16*)A;
  #pragma unroll
  for (int mg=0;mg<4;mg++){
    #pragma unroll
    for (int r=0;r<4;r++){
      int row_l = wave*64 + mg*16 + q*4 + r;
      int row   = n0 + row_l;
      #pragma unroll
      for (int ng=0;ng<4;ng++){
        int col = ng*16 + ml;
        float rv = sigm(acc[mg][ng][r] + br[col]);
        float hv = bf2f(h[(size_t)row*64 + col]);
        h_old[mg][ng][r] = hv;
        int kk = 64 + col;
        int c2 = kk>>5, q2 = (kk>>3)&3, j2 = kk&7;
        As[ (((row_l>>4)*4 + c2)*64 + q2*16 + (row_l&15))*8 + j2 ] = f2bf(hv*rv);
      }
    }
  }
  // no __syncthreads: wave-local rows only (lgkmcnt orders LDS ops).

  load_b<4>(pc_, 0, lane, Bf);
  zero_acc(acc);
  mfma_tile<4>(A, Bf, acc, wave, lane);

  #pragma unroll
  for (int mg=0;mg<4;mg++)
    #pragma unroll
    for (int r=0;r<4;r++){
      int row_l = wave*64 + mg*16 + q*4 + r;
      int row   = n0 + row_l;
      #pragma unroll
      for (int ng=0;ng<4;ng++){
        int col = ng*16 + ml;
        float zv = sigm(zacc[mg][ng][r] + bz[col]);
        float cv = tanhf(acc[mg][ng][r] + bc_[col]);
        float ho = h_old[mg][ng][r];
        float hn = (1.f - zv)*ho + zv*cv;
        if (nodew == nullptr){
          h[(size_t)row*64 + col] = f2bf(hn);
        } else {
          int kk = 64 + col;
          int c2 = kk>>5, q2 = (kk>>3)&3, j2 = kk&7;
          As[ (((row_l>>4)*4 + c2)*64 + q2*16 + (row_l&15))*8 + j2 ] = f2bf(hn);
        }
      }
    }

  if (nodew){
    short8 Bd[2][4];
    load_b<2>(pd1, 0, lane, Bd);
    floatx4 dacc[4][4];
    zero_acc(dacc);
    #pragma unroll
    for (int c=0;c<2;c++){
      #pragma unroll
      for (int mg=0;mg<4;mg++){
        short8 a = A[((wave*4+mg)*4 + (2+c))*64 + lane];
        #pragma unroll
        for (int ng=0;ng<4;ng++)
          dacc[mg][ng] = __builtin_amdgcn_mfma_f32_16x16x32_bf16(a, Bd[c][ng], dacc[mg][ng], 0, 0, 0);
      }
    }
    float wd2l[4];
    #pragma unroll
    for (int ng=0;ng<4;ng++) wd2l[ng] = Wd2[ng*16 + ml];
    float b2 = bd2[0];
    #pragma unroll
    for (int mg=0;mg<4;mg++)
      #pragma unroll
      for (int r=0;r<4;r++){
        int row = n0 + wave*64 + mg*16 + q*4 + r;
        float ps = 0.f;
        #pragma unroll
        for (int ng=0;ng<4;ng++)
          ps += tanhf(dacc[mg][ng][r] + bd1[ng*16+ml]) * wd2l[ng];
        #pragma unroll
        for (int s=1;s<16;s<<=1) ps += __shfl_xor(ps, s, 64);
        if (ml == 0) nodew[row] = ps + b2;
      }
  }
}

// ===== edge softmax + nv0 + INLINE bucket build (atomic floor ~67us) =====
__global__ __launch_bounds__(256) void k_pw(
    const int* __restrict__ adj, const float* __restrict__ nodew, const float* __restrict__ dem,
    float* __restrict__ normw, float* __restrict__ nv0,
    u32* __restrict__ cnt, u32* __restrict__ bucket, float* __restrict__ cost)
{
  if (blockIdx.x == 0 && threadIdx.x < BN) cost[threadIdx.x] = 0.f;
  const int bid = blockIdx.x;
  const int b   = (bid & 7) >> 1;                    // batch from XCD
  const int loc = (bid >> 3)*2 + (bid & 1);          // 0..1023
  int node = b*VN + loc*16 + (threadIdx.x >> 4);
  int e = node*16 + (threadIdx.x & 15);
  int u = adj[e];
  float pw = (u == VN) ? NEGC : nodew[(size_t)b*VN + u];
  float mx = pw;
  #pragma unroll
  for (int s=1;s<16;s<<=1) mx = fmaxf(mx, __shfl_xor(mx, s, 64));
  float ex = expf(pw - mx);
  float sm = ex;
  #pragma unroll
  for (int s=1;s<16;s<<=1) sm += __shfl_xor(sm, s, 64);
  float nw = ex / sm;
  normw[e] = nw;
  if ((e & 15) == 0) nv0[node] = fmaxf(-dem[node], 0.f);
  if (u < VN){
    int g = b*VN + u;
    u32 pos = atomicAdd(&cnt[g], 1u);
    if (pos < CAP)
      bucket[(size_t)g*CAP + pos] = ((u32)f2bf(nw) << 16) | (u32)(node & (VN-1));
  }
}

// ========== solver iteration: bucket gather; XCD swizzle; fused flow ==========
__global__ __launch_bounds__(256) void k_gather(
    const u32* __restrict__ cnt, const u32* __restrict__ bucket,
    const float* __restrict__ dem, const float* __restrict__ nvin, float* __restrict__ nvout,
    const float* __restrict__ normw, float* __restrict__ fout, float* __restrict__ cost)
{
  const int bid = blockIdx.x;
  const int b   = (bid & 7) >> 1;                    // batch from XCD
  const int loc = (bid >> 3)*2 + (bid & 1);          // 0..1023
  int g = b*VN + loc*16 + (threadIdx.x >> 4);
  int lane = threadIdx.x & 15;
  u32 n = cnt[g];
  if (n > CAP) n = CAP;
  const u32* bk = bucket + (size_t)g*CAP;
  const float* nb = nvin + (size_t)b*VN;
  float sum = 0.f;
  for (u32 i = (u32)lane; i < n; i += 16u){
    u32 r = bk[i];
    sum += bf2f(r >> 16) * nb[r & 0xFFFFu];
  }
  #pragma unroll
  for (int sh=1; sh<16; sh<<=1) sum += __shfl_xor(sum, sh, 64);
  float nvv = fmaxf(sum - dem[g], 0.f);
  if (lane == 0) nvout[g] = nvv;
  if (fout){
    int e = g*16 + lane;
    float fl = normw[e] * nvv;
    fout[e] = fl;
    if (cost){
      float ssq = fl*fl;
      #pragma unroll
      for (int sh=1; sh<64; sh<<=1) ssq += __shfl_xor(ssq, sh, 64);
      __shared__ float part[4];
      if ((threadIdx.x & 63) == 0) part[threadIdx.x>>6] = ssq;
      __syncthreads();
      if (threadIdx.x == 0) atomicAdd(cost + b, part[0]+part[1]+part[2]+part[3]);
    }
  }
}

// ================= launcher =================
extern "C" void kernel_launch(void* const* d_in, const int* in_sizes, int n_in,
                              void* d_out, int out_size, void* d_ws, size_t ws_size,
                              hipStream_t stream)
{
  const float* emb  = (const float*)d_in[0];
  const float* feat = (const float*)d_in[1];
  const float* dem  = (const float*)d_in[2];
  const int*   adj  = (const int*)  d_in[3];
  const float* We1 = (const float*)d_in[6];
  const float* be1 = (const float*)d_in[7];
  const float* We2 = (const float*)d_in[8];
  const float* be2 = (const float*)d_in[9];
  const float* Wg  = (const float*)d_in[10];
  const float* asrc= (const float*)d_in[11];
  const float* adst= (const float*)d_in[12];
  const float* Wz  = (const float*)d_in[13];
  const float* Uz  = (const float*)d_in[14];
  const float* bz  = (const float*)d_in[15];
  const float* Wr  = (const float*)d_in[16];
  const float* Ur  = (const float*)d_in[17];
  const float* br  = (const float*)d_in[18];
  const float* Wc  = (const float*)d_in[19];
  const float* Uc  = (const float*)d_in[20];
  const float* bc  = (const float*)d_in[21];
  const float* Wd1 = (const float*)d_in[22];
  const float* bd1 = (const float*)d_in[23];
  const float* Wd2 = (const float*)d_in[24];
  const float* bd2 = (const float*)d_in[25];

  char* ws = (char*)d_ws;
  u16*   h     = (u16*)  (ws + OFF_H);
  u16*   m     = (u16*)  (ws + OFF_M);
  u32*   tq    = (u32*)  (ws + OFF_T);          // fp8 t-table, [NN+1][64] u32
  u32*   bucket= (u32*)  (ws + OFF_T);          // overlays t after attn done
  float* ss    = (float*)(ws + OFF_SS);
  float* nodew = (float*)(ws + OFF_NW);
  float* nv    = (float*)(ws + OFF_NV);         // [2][NN]
  u32*   cnt   = (u32*)  (ws + OFF_CNT);
  u16* pg  = (u16*)(ws + OFF_PG);
  u16* pzr = (u16*)(ws + OFF_PZR);
  u16* pc  = (u16*)(ws + OFF_PC);
  u16* pe1 = (u16*)(ws + OFF_PE1);
  u16* pe2 = (u16*)(ws + OFF_PE2);
  u16* pd1 = (u16*)(ws + OFF_PD1);
  u16* pav = (u16*)(ws + OFF_PAV);
  float* nv0b = nv;
  float* nv1b = nv + NN;

  float* out0 = (float*)d_out;            // flow   [B,V,K]  (= f10)
  float* out1 = out0 + 1048576;           // flow_cost [B]
  float* out2 = out0 + 1048580;           // norm_w [B,V,K]
  float* out3 = out0 + 2097156;           // pflow  [B,V,K]  (= f9)

  k_pack<<<212, 256, 0, stream>>>(Wg, Wz, Uz, Wr, Ur, Wc, Uc, We1, We2, Wd1,
                                  asrc, adst, pg, pzr, pc, pe1, pe2, pd1, pav);
  k_enc<<<512, 128, 0, stream>>>(emb, feat, pe1, pe2, be1, be2, h, cnt);

  for (int l=0; l<2; ++l){
    k_t   <<<512, 128, 0, stream>>>(h, pg, pav, tq, ss);
    k_attn<<<16384, 256, 0, stream>>>(adj, tq, ss, m);
    k_gru <<<512, 128, 0, stream>>>(m, h, pzr, pc, bz, br, bc,
                                    pd1, bd1, Wd2, bd2, (l==1) ? nodew : nullptr);
  }

  // bucket overlays the t region (t is dead now)
  k_pw <<<4096, 256, 0, stream>>>(adj, nodew, dem, out2, nv0b, cnt, bucket, out1);

  // 10 gather iterations; pflow fused into i=9, flow+cost into i=10
  for (int i=1; i<=10; ++i){
    float* in  = (i & 1) ? nv0b : nv1b;
    float* out = (i & 1) ? nv1b : nv0b;
    float* fo  = (i==10) ? out0 : ((i==9) ? out3 : nullptr);
    k_gather<<<4096, 256, 0, stream>>>(cnt, bucket, dem, in, out, out2, fo,
                                       (i==10) ? out1 : nullptr);
  }
}